// Round 4
// baseline (4429.520 us; speedup 1.0000x reference)
//
#include <hip/hip_runtime.h>

typedef __bf16 bf16_t;
typedef __bf16 bf16x8v __attribute__((ext_vector_type(8)));
typedef float f32x4 __attribute__((ext_vector_type(4)));

#define CB 4
#define CS 1024
#define CE 768
#define CH 12
#define CD 64

// load 8 elements as bf16 into dst (16B). T = float (converts) or bf16 (raw).
template<typename T>
__device__ __forceinline__ void ld8(bf16_t* dst, const T* src) {
    if constexpr (sizeof(T) == 2) {
        *(uint4*)dst = *(const uint4*)src;
    } else {
        const float4 a = *(const float4*)src;
        const float4 b = *(const float4*)(src + 4);
        bf16_t t0[8] = {(bf16_t)a.x, (bf16_t)a.y, (bf16_t)a.z, (bf16_t)a.w,
                        (bf16_t)b.x, (bf16_t)b.y, (bf16_t)b.z, (bf16_t)b.w};
        *(uint4*)dst = *(uint4*)t0;
    }
}

// ===== generic MFMA GEMM =====
// A0/A1: [M,K] row-major (lda). CONCAT: kk<768 -> A0, kk>=768 -> A1 (both lda).
// B: BT=0 -> [N,K] (ldb = K-dim stride); BT=1 -> [K,N] natural weights (ldb = N-dim stride).
// ACT: 0 none, 1 sigmoid, 2 gelu. RES: 0 none, 2 += f32 resid[idx].
// OUT: 0 bf16 C, 1 f32 C.
// CMODE: 0 C+=z*sC; 1 C += (z/CH)*sCb+(z%CH)*sCh (head-merge); 2 split [b,H,s,d];
//        3 split [b,H,d,s]; 4 qkv: q->C [b,H,s,d], k->C2 [b,H,s,d], v->C3 [b,H,d,s].
// BMODE: 0 B += z*sB ; 1 B += (z%CH)*sB.
template<int BM, int BN, typename TA0, typename TA1, typename TB, int BT, int CONCAT,
         int ACT, int RES, int OUT, int CMODE, int BMODE>
__global__ __launch_bounds__(256)
void gemm_k(const TA0* __restrict__ A0, const TA1* __restrict__ A1,
            const TB* __restrict__ B, const float* __restrict__ bias,
            const void* __restrict__ resid,
            void* __restrict__ C, void* __restrict__ C2, void* __restrict__ C3,
            int M, int N, int K, int lda, int ldb,
            long sA, long sB, long sC, int ldc, long sCb, long sCh)
{
    constexpr int WM = BM / 2, WN = BN / 2, RM = WM / 16, RN = WN / 16;
    constexpr int PK = 40;
    __shared__ bf16_t As[BM * PK];
    __shared__ bf16_t Bs[BN * PK];

    const int t = threadIdx.x;
    const int z = blockIdx.z;
    const int m0 = blockIdx.y * BM, n0 = blockIdx.x * BN;
    const TA0* Ab = A0 + (long)z * sA;
    const TB* Bb = B + ((BMODE == 1) ? (long)(z % CH) * sB : (long)z * sB);

    const int ar = t >> 2, ac = (t & 3) * 8;
    const int lane = t & 63, wave = t >> 6;
    const int wm = (wave & 1) * WM, wn = (wave >> 1) * WN;
    const int fr = lane & 15, fq = (lane >> 4) * 8;

    f32x4 acc[RM][RN];
#pragma unroll
    for (int i = 0; i < RM; i++)
#pragma unroll
        for (int j = 0; j < RN; j++)
#pragma unroll
            for (int p = 0; p < 4; p++) acc[i][j][p] = 0.f;

    for (int kt = 0; kt < K; kt += 32) {
        // ---- stage A ----
#pragma unroll
        for (int r = ar; r < BM; r += 64) {
            int kk = kt + ac;
            if (CONCAT && kk >= 768)
                ld8(&As[r * PK + ac], &A1[(long)(m0 + r) * lda + (kk - 768)]);
            else
                ld8(&As[r * PK + ac], &Ab[(long)(m0 + r) * lda + kk]);
        }
        // ---- stage B ----
        if (BT == 0) {
#pragma unroll
            for (int r = ar; r < BN; r += 64)
                ld8(&Bs[r * PK + ac], &Bb[(long)(n0 + r) * ldb + kt + ac]);
        } else {
            constexpr int TPR = BN / 8;
            constexpr int KROWS = 256 / TPR;
            const int kr = t / TPR, nc = (t % TPR) * 8;
#pragma unroll
            for (int kk = kr; kk < 32; kk += KROWS) {
                bf16_t tmp[8];
                ld8(tmp, &Bb[(long)(kt + kk) * ldb + n0 + nc]);
#pragma unroll
                for (int i = 0; i < 8; i++) Bs[(nc + i) * PK + kk] = tmp[i];
            }
        }
        __syncthreads();

        bf16x8v af[RM], bfr[RN];
#pragma unroll
        for (int i = 0; i < RM; i++)
            af[i] = *(const bf16x8v*)&As[(wm + i * 16 + fr) * PK + fq];
#pragma unroll
        for (int j = 0; j < RN; j++)
            bfr[j] = *(const bf16x8v*)&Bs[(wn + j * 16 + fr) * PK + fq];
#pragma unroll
        for (int i = 0; i < RM; i++)
#pragma unroll
            for (int j = 0; j < RN; j++)
                acc[i][j] = __builtin_amdgcn_mfma_f32_16x16x32_bf16(af[i], bfr[j], acc[i][j], 0, 0, 0);
        __syncthreads();
    }

    long coff = 0;
    if (CMODE == 0) coff = (long)z * sC;
    if (CMODE == 1) coff = (long)(z / CH) * sCb + (long)(z % CH) * sCh;
    const int rq = (lane >> 4) * 4, cn = lane & 15;
#pragma unroll
    for (int i = 0; i < RM; i++)
#pragma unroll
        for (int j = 0; j < RN; j++) {
            int col = n0 + wn + j * 16 + cn;
            float bv = bias ? bias[col] : 0.f;
#pragma unroll
            for (int p = 0; p < 4; p++) {
                int row = m0 + wm + i * 16 + rq + p;
                float v = acc[i][j][p] + bv;
                if (ACT == 1) v = 1.f / (1.f + __expf(-v));
                if (ACT == 2) {
                    float u = 0.7978845608028654f * (v + 0.044715f * v * v * v);
                    v = 0.5f * v * (1.f + tanhf(u));
                }
                if (CMODE <= 1) {
                    long idx = coff + (long)row * ldc + col;
                    if (RES == 2) v += ((const float*)resid)[idx];
                    if (OUT == 0) ((bf16_t*)C)[idx] = (bf16_t)v;
                    else          ((float*)C)[idx] = v;
                } else {
                    int bb = row >> 10, ss = row & 1023;
                    int t3 = (CMODE == 4) ? (col / 768) : 0;
                    int cc = col - t3 * 768;
                    int hh = cc >> 6, dd = cc & 63;
                    long sidx = (((long)(bb * CH + hh) * 1024) + ss) * 64 + dd;
                    long tidx = (((long)(bb * CH + hh) * 64) + dd) * 1024 + ss;
                    if (CMODE == 2)      ((bf16_t*)C)[sidx] = (bf16_t)v;
                    else if (CMODE == 3) ((bf16_t*)C)[tidx] = (bf16_t)v;
                    else {
                        if (t3 == 0)      ((bf16_t*)C)[sidx]  = (bf16_t)v;
                        else if (t3 == 1) ((bf16_t*)C2)[sidx] = (bf16_t)v;
                        else              ((bf16_t*)C3)[tidx] = (bf16_t)v;
                    }
                }
            }
        }
}

// ===== LayerNorm rows of 768 (f32 in, bf16 out) =====
__global__ __launch_bounds__(256)
void ln_kernel(const float* __restrict__ in, bf16_t* __restrict__ out,
               const float* __restrict__ g, const float* __restrict__ b,
               int RC, long cstride)
{
    __shared__ float red[4];
    const int r = blockIdx.x, t = threadIdx.x;
    const long base = (long)(r / RC) * cstride + (long)(r % RC) * CE;
    float v0 = in[base + t], v1 = in[base + t + 256], v2 = in[base + t + 512];
    float s = v0 + v1 + v2;
    for (int m = 32; m; m >>= 1) s += __shfl_xor(s, m, 64);
    if ((t & 63) == 0) red[t >> 6] = s;
    __syncthreads();
    s = red[0] + red[1] + red[2] + red[3];
    __syncthreads();
    const float mu = s * (1.f / 768.f);
    float d0 = v0 - mu, d1 = v1 - mu, d2 = v2 - mu;
    float q = d0 * d0 + d1 * d1 + d2 * d2;
    for (int m = 32; m; m >>= 1) q += __shfl_xor(q, m, 64);
    if ((t & 63) == 0) red[t >> 6] = q;
    __syncthreads();
    q = red[0] + red[1] + red[2] + red[3];
    const float rstd = rsqrtf(q * (1.f / 768.f) + 1e-5f);
    const long ob = (long)r * CE;
    out[ob + t]       = (bf16_t)(g[t]       * d0 * rstd + b[t]);
    out[ob + t + 256] = (bf16_t)(g[t + 256] * d1 * rstd + b[t + 256]);
    out[ob + t + 512] = (bf16_t)(g[t + 512] * d2 * rstd + b[t + 512]);
}

// ===== row softmax (in-place bf16) =====
template<int VPT>
__global__ void softmax_kernel(bf16_t* __restrict__ buf, int L, int nvalid, float scale,
                               const int* __restrict__ mask)
{
    __shared__ float red[4];
    const int bt = blockDim.x;
    const long r = blockIdx.x;
    bf16_t* row = buf + r * (long)L;
    const int t = threadIdx.x;
    const int nw = bt >> 6;

    float x[VPT];
#pragma unroll
    for (int i = 0; i < VPT; i++) {
        int c = t + i * bt;
        float v = (float)row[c] * scale;
        if (mask && mask[c]) v = -10000.f;
        if (c >= nvalid) v = -1e30f;
        x[i] = v;
    }
    float m = x[0];
#pragma unroll
    for (int i = 1; i < VPT; i++) m = fmaxf(m, x[i]);
    for (int mm = 32; mm; mm >>= 1) m = fmaxf(m, __shfl_xor(m, mm, 64));
    if ((t & 63) == 0) red[t >> 6] = m;
    __syncthreads();
    m = red[0];
    for (int w = 1; w < nw; w++) m = fmaxf(m, red[w]);
    __syncthreads();
    float s = 0.f;
#pragma unroll
    for (int i = 0; i < VPT; i++) { x[i] = __expf(x[i] - m); s += x[i]; }
    for (int mm = 32; mm; mm >>= 1) s += __shfl_xor(s, mm, 64);
    if ((t & 63) == 0) red[t >> 6] = s;
    __syncthreads();
    s = 0.f;
    for (int w = 0; w < nw; w++) s += red[w];
    const float inv = 1.f / s;
#pragma unroll
    for (int i = 0; i < VPT; i++) {
        int c = t + i * bt;
        row[c] = (bf16_t)((c < nvalid) ? x[i] * inv : 0.f);
    }
}

// ===== elementwise =====
__global__ void blend_kernel(const bf16_t* __restrict__ al, bf16_t* __restrict__ a,
                             const bf16_t* __restrict__ a1)
{   // a = al*a + (1-al)*a1 (in place)
    int idx = blockIdx.x * 256 + threadIdx.x;
    float g = (float)al[idx];
    a[idx] = (bf16_t)(g * (float)a[idx] + (1.f - g) * (float)a1[idx]);
}

__global__ void gate_part1(const bf16_t* __restrict__ al, const float* __restrict__ rf,
                           const bf16_t* __restrict__ eb, bf16_t* __restrict__ t1)
{   // t1 = al*r + (1-al)*e
    int idx = blockIdx.x * 256 + threadIdx.x;
    float g = (float)al[idx];
    t1[idx] = (bf16_t)(g * rf[idx] + (1.f - g) * (float)eb[idx]);
}

__global__ void gate_part2(const bf16_t* __restrict__ al, float* __restrict__ rf,
                           const bf16_t* __restrict__ eb, const bf16_t* __restrict__ t1)
{   // rf = 0.7071*(t1 + al*r + (1-al)*e)   (in place over rf)
    int idx = blockIdx.x * 256 + threadIdx.x;
    float g = (float)al[idx];
    float v = (float)t1[idx] + g * rf[idx] + (1.f - g) * (float)eb[idx];
    rf[idx] = v * 0.7071067811865476f;
}

__global__ void zero_out(float* __restrict__ out)
{
    out[blockIdx.x * 256 + threadIdx.x] = 0.f;
}

__global__ void mem_gemm(const float* __restrict__ memf, const float* __restrict__ W,
                         const float* __restrict__ bias, bf16_t* __restrict__ out)
{   // out[100][1536] = memf[100][768] @ W[768][1536] + bias
    int idx = blockIdx.x * 256 + threadIdx.x;
    int n = idx % 1536, m = idx / 1536;
    float acc = bias[n];
    for (int k = 0; k < 768; k++)
        acc += memf[m * 768 + k] * W[(long)k * 1536 + n];
    out[idx] = (bf16_t)acc;
}

__global__ void repack_mem(const bf16_t* __restrict__ mem, bf16_t* __restrict__ mkt,
                           bf16_t* __restrict__ mvt)
{   // mkt[h][slot(128)][d] ; mvt[h][d][slot(128)] ; pad slots 100..127 with 0
    int idx = blockIdx.x * 256 + threadIdx.x;
    int d = idx & 63;
    int slot = (idx >> 6) & 127;
    int h = idx >> 13;
    bf16_t kv = (slot < 100) ? mem[slot * 1536 + h * CD + d] : (bf16_t)0.f;
    bf16_t vv = (slot < 100) ? mem[slot * 1536 + CE + h * CD + d] : (bf16_t)0.f;
    mkt[idx] = kv;
    mvt[((long)h * 64 + d) * 128 + slot] = vv;
}

// ===================================================================================
extern "C" void kernel_launch(void* const* d_in, const int* in_sizes, int n_in,
                              void* d_out, int out_size, void* d_ws, size_t ws_size,
                              hipStream_t stream)
{
    (void)in_sizes; (void)n_in; (void)out_size;
    const float* x        = (const float*)d_in[0];
    const float* encf     = (const float*)d_in[1];
    const int*   maskenc  = (const int*)d_in[2];
    const float* ln1_g    = (const float*)d_in[3];
    const float* ln1_b    = (const float*)d_in[4];
    const float* ln2_g    = (const float*)d_in[5];
    const float* ln2_b    = (const float*)d_in[6];
    const float* c_attn_w = (const float*)d_in[7];
    const float* c_attn_b = (const float*)d_in[8];
    const float* aproj_w  = (const float*)d_in[9];
    const float* aproj_b  = (const float*)d_in[10];
    const float* memf     = (const float*)d_in[11];
    const float* mattn_w  = (const float*)d_in[12];
    const float* mattn_b  = (const float*)d_in[13];
    const float* malpha_w = (const float*)d_in[14];
    const float* malpha_b = (const float*)d_in[15];
    const float* fcq_w    = (const float*)d_in[16];
    const float* fcq_b    = (const float*)d_in[17];
    const float* fck_w    = (const float*)d_in[18];
    const float* fck_b    = (const float*)d_in[19];
    const float* fcv_w    = (const float*)d_in[20];
    const float* fcv_b    = (const float*)d_in[21];
    const float* eproj_w  = (const float*)d_in[22];
    const float* eproj_b  = (const float*)d_in[23];
    const float* fa1_w    = (const float*)d_in[24];
    const float* fa1_b    = (const float*)d_in[25];
    const float* fa2_w    = (const float*)d_in[26];
    const float* fa2_b    = (const float*)d_in[27];
    const float* mfc_w    = (const float*)d_in[28];
    const float* mfc_b    = (const float*)d_in[29];
    const float* mproj_w  = (const float*)d_in[30];
    const float* mproj_b  = (const float*)d_in[31];
    float* dout = (float*)d_out;

    size_t off = 0;
    auto alloc = [&](size_t bytes) -> void* {
        void* p = (char*)d_ws + off;
        off = (off + bytes + 255) & ~(size_t)255;
        return p;
    };
    const size_t SZ = (size_t)4096 * 768 * 2;           // 6.29 MB (bf16 [4096,768])
    bf16_t* membuf = (bf16_t*)alloc((size_t)100 * 1536 * 2);
    bf16_t* mkt    = (bf16_t*)alloc((size_t)CH * 128 * 64 * 2);
    bf16_t* mvt    = (bf16_t*)alloc((size_t)CH * 64 * 128 * 2);
    bf16_t* bufA   = (bf16_t*)alloc(SZ);                 // LN out / al gates / mlp LN
    bf16_t* qbuf   = (bf16_t*)alloc(SZ);                 // q [b,H,s,d]
    bf16_t* kbuf   = (bf16_t*)alloc(SZ);                 // k [b,H,s,d]
    bf16_t* vtbuf  = (bf16_t*)alloc(SZ);                 // v [b,H,d,s]
    bf16_t* scores = (bf16_t*)alloc((size_t)3 * 1024 * 1024 * 2); // chunk / mem-scores / mid
    bf16_t* asbuf  = (bf16_t*)alloc(SZ);                 // merged attn out (blend in-place)
    bf16_t* ebuf   = (bf16_t*)alloc(SZ);                 // mem-attn out / e_i
    bf16_t* t1buf  = (bf16_t*)alloc(SZ);                 // gate partial
    float*  residf = (float*)alloc((size_t)4096 * 768 * 4); // a (f32); becomes a2 in place

    if (off > ws_size) {   // ws too small -> finite diagnostic (absmax = max|ref| = 4.72)
        zero_out<<<12288, 256, 0, stream>>>(dout);
        return;
    }

    const dim3 blk(256);
    const long HB = (long)1024 * 64;     // per-head q/k/v block
    const long RB = (long)1024 * 768;    // per-batch row block
    const long SB = (long)1024 * 1024;   // per-head score block

    mem_gemm<<<600, blk, 0, stream>>>(memf, mattn_w, mattn_b, membuf);
    repack_mem<<<384, blk, 0, stream>>>(membuf, mkt, mvt);

    // h = LN1(x); qkv gemm (fp32 weights transposed+cast during staging), fused head split
    ln_kernel<<<4096, blk, 0, stream>>>(x, bufA, ln1_g, ln1_b, 4096, 0);
    gemm_k<128,128,bf16_t,bf16_t,float,1,0,0,0,0,4,0><<<dim3(18, 32, 1), blk, 0, stream>>>(
        bufA, nullptr, c_attn_w, c_attn_b, nullptr, qbuf, kbuf, vtbuf,
        4096, 2304, 768, 768, 2304, 0, 0, 0, 0, 0, 0);

    // ---- self attention (no 1/sqrt(d) scale), chunk = batch x 3-head group ----
    for (int b = 0; b < CB; b++)
        for (int hg = 0; hg < 4; hg++) {
            const long ho = ((long)b * CH + hg * 3) * HB;
            gemm_k<128,128,bf16_t,bf16_t,bf16_t,0,0,0,0,0,0,0><<<dim3(8, 8, 3), blk, 0, stream>>>(
                qbuf + ho, nullptr, kbuf + ho, nullptr, nullptr, scores, nullptr, nullptr,
                1024, 1024, 64, 64, 64, HB, HB, SB, 1024, 0, 0);
            softmax_kernel<4><<<3072, blk, 0, stream>>>(scores, 1024, 1024, 1.f, nullptr);
            gemm_k<128,64,bf16_t,bf16_t,bf16_t,0,0,0,0,0,1,0><<<dim3(1, 8, 3), blk, 0, stream>>>(
                scores, nullptr, vtbuf + ho, nullptr, nullptr,
                asbuf + (long)b * RB + hg * 192, nullptr, nullptr,
                1024, 64, 1024, 1024, 1024, SB, HB, 0, 768, 0, 64);
        }

    // ---- memory attention (padded to 128 slots), chunk = 2 batches ----
    for (int c = 0; c < 2; c++) {
        const long qo = (long)c * 24 * HB;
        gemm_k<128,128,bf16_t,bf16_t,bf16_t,0,0,0,0,0,0,1><<<dim3(1, 8, 24), blk, 0, stream>>>(
            qbuf + qo, nullptr, mkt, nullptr, nullptr, scores, nullptr, nullptr,
            1024, 128, 64, 64, 64, HB, (long)128 * 64, (long)1024 * 128, 128, 0, 0);
        softmax_kernel<1><<<24576, 128, 0, stream>>>(scores, 128, 100, 1.f, nullptr);
        gemm_k<128,64,bf16_t,bf16_t,bf16_t,0,0,0,0,0,1,1><<<dim3(1, 8, 24), blk, 0, stream>>>(
            scores, nullptr, mvt, nullptr, nullptr, ebuf + (long)c * 2 * RB, nullptr, nullptr,
            1024, 64, 128, 128, 128, (long)1024 * 128, (long)64 * 128, 0, 768, RB, 64);
    }

    // ---- memory gate (concat fused) + blend + attn proj + residual ----
    gemm_k<128,128,bf16_t,bf16_t,float,1,1,1,0,0,0,0><<<dim3(6, 32, 1), blk, 0, stream>>>(
        asbuf, ebuf, malpha_w, malpha_b, nullptr, bufA, nullptr, nullptr,
        4096, 768, 1536, 768, 768, 0, 0, 0, 768, 0, 0);
    blend_kernel<<<12288, blk, 0, stream>>>(bufA, asbuf, ebuf);
    gemm_k<128,128,bf16_t,bf16_t,float,1,0,0,2,1,0,0><<<dim3(6, 32, 1), blk, 0, stream>>>(
        asbuf, nullptr, aproj_w, aproj_b, x, residf, nullptr, nullptr,
        4096, 768, 768, 768, 768, 0, 0, 0, 768, 0, 0);

    // ---- cross attention: ha, qe ----
    ln_kernel<<<4096, blk, 0, stream>>>(residf, bufA, ln1_g, ln1_b, 4096, 0);
    gemm_k<128,128,bf16_t,bf16_t,float,1,0,0,0,0,2,0><<<dim3(6, 32, 1), blk, 0, stream>>>(
        bufA, nullptr, fcq_w, fcq_b, nullptr, qbuf, nullptr, nullptr,
        4096, 768, 768, 768, 768, 0, 0, 0, 0, 0, 0);

    for (int e = 0; e < 2; e++) {
        ln_kernel<<<4096, blk, 0, stream>>>(
            encf + (size_t)e * RB, bufA, ln1_g, ln1_b, 1024, (long)2 * RB);
        gemm_k<128,128,bf16_t,bf16_t,float,1,0,0,0,0,2,0><<<dim3(6, 32, 1), blk, 0, stream>>>(
            bufA, nullptr, fck_w, fck_b, nullptr, kbuf, nullptr, nullptr,
            4096, 768, 768, 768, 768, 0, 0, 0, 0, 0, 0);
        gemm_k<128,128,bf16_t,bf16_t,float,1,0,0,0,0,3,0><<<dim3(6, 32, 1), blk, 0, stream>>>(
            bufA, nullptr, fcv_w, fcv_b, nullptr, vtbuf, nullptr, nullptr,
            4096, 768, 768, 768, 768, 0, 0, 0, 0, 0, 0);
        for (int b = 0; b < CB; b++)
            for (int hg = 0; hg < 4; hg++) {
                const long ho = ((long)b * CH + hg * 3) * HB;
                gemm_k<128,128,bf16_t,bf16_t,bf16_t,0,0,0,0,0,0,0><<<dim3(8, 8, 3), blk, 0, stream>>>(
                    qbuf + ho, nullptr, kbuf + ho, nullptr, nullptr, scores, nullptr, nullptr,
                    1024, 1024, 64, 64, 64, HB, HB, SB, 1024, 0, 0);
                softmax_kernel<4><<<3072, blk, 0, stream>>>(
                    scores, 1024, 1024, 0.125f, maskenc + (size_t)b * 1024);
                gemm_k<128,64,bf16_t,bf16_t,bf16_t,0,0,0,0,0,1,0><<<dim3(1, 8, 3), blk, 0, stream>>>(
                    scores, nullptr, vtbuf + ho, nullptr, nullptr,
                    asbuf + (long)b * RB + hg * 192, nullptr, nullptr,
                    1024, 64, 1024, 1024, 1024, SB, HB, 0, 768, 0, 64);
            }
        gemm_k<128,128,bf16_t,bf16_t,float,1,0,0,0,0,0,0><<<dim3(6, 32, 1), blk, 0, stream>>>(
            asbuf, nullptr, eproj_w, eproj_b, nullptr, ebuf, nullptr, nullptr,
            4096, 768, 768, 768, 768, 0, 0, 0, 768, 0, 0);
        // gate: al_e = sigmoid(concat(a, e_e) @ fa_e + b)   (A0 = fp32 residual)
        gemm_k<128,128,float,bf16_t,float,1,1,1,0,0,0,0><<<dim3(6, 32, 1), blk, 0, stream>>>(
            residf, ebuf, (e == 0 ? fa1_w : fa2_w), (e == 0 ? fa1_b : fa2_b), nullptr,
            bufA, nullptr, nullptr,
            4096, 768, 1536, 768, 768, 0, 0, 0, 768, 0, 0);
        if (e == 0) gate_part1<<<12288, blk, 0, stream>>>(bufA, residf, ebuf, t1buf);
        else        gate_part2<<<12288, blk, 0, stream>>>(bufA, residf, ebuf, t1buf);
    }
    // residf now holds a2 (f32)

    // ---- MLP, M-chunked x4 so mid fits scores buffer ----
    ln_kernel<<<4096, blk, 0, stream>>>(residf, bufA, ln2_g, ln2_b, 4096, 0);
    for (int mc = 0; mc < 4; mc++) {
        gemm_k<128,128,bf16_t,bf16_t,float,1,0,2,0,0,0,0><<<dim3(24, 8, 1), blk, 0, stream>>>(
            bufA + (long)mc * RB, nullptr, mfc_w, mfc_b, nullptr, scores, nullptr, nullptr,
            1024, 3072, 768, 768, 3072, 0, 0, 0, 3072, 0, 0);
        gemm_k<128,128,bf16_t,bf16_t,float,1,0,0,2,1,0,0><<<dim3(6, 8, 1), blk, 0, stream>>>(
            scores, nullptr, mproj_w, mproj_b, residf + (long)mc * RB,
            dout + (long)mc * RB, nullptr, nullptr,
            1024, 768, 3072, 3072, 768, 0, 0, 0, 768, 0, 0);
    }
}

// Round 5
// 1068.399 us; speedup vs baseline: 4.1459x; 4.1459x over previous
//
#include <hip/hip_runtime.h>

typedef __bf16 bf16_t;
typedef __bf16 bf16x8v __attribute__((ext_vector_type(8)));
typedef float f32x4 __attribute__((ext_vector_type(4)));

#define CB 4
#define CS 1024
#define CE 768
#define CH 12
#define CD 64

// load 8 elements as bf16 into dst (16B). T = float (converts) or bf16 (raw).
template<typename T>
__device__ __forceinline__ void ld8(bf16_t* dst, const T* src) {
    if constexpr (sizeof(T) == 2) {
        *(uint4*)dst = *(const uint4*)src;
    } else {
        const float4 a = *(const float4*)src;
        const float4 b = *(const float4*)(src + 4);
        bf16_t t0[8] = {(bf16_t)a.x, (bf16_t)a.y, (bf16_t)a.z, (bf16_t)a.w,
                        (bf16_t)b.x, (bf16_t)b.y, (bf16_t)b.z, (bf16_t)b.w};
        *(uint4*)dst = *(uint4*)t0;
    }
}

// ===== MFMA GEMM, B pre-transposed [N,K] bf16 =====
// CONCAT: kk<768 -> A0, kk>=768 -> A1 (both lda). ACT: 0 none,1 sigmoid,2 gelu.
// RES: 0 none, 2 += f32 resid. OUT: 0 bf16, 1 f32.
// CMODE: 0 normal (ldc); 2 head-split [b,H,s,d]; 3 [b,H,d,s]; 4 qkv->C,C2,C3.
template<int BM, int BN, typename TA0, typename TA1, int CONCAT, int ACT, int RES,
         int OUT, int CMODE>
__global__ __launch_bounds__(256)
void gemm_n(const TA0* __restrict__ A0, const TA1* __restrict__ A1,
            const bf16_t* __restrict__ Bt, const float* __restrict__ bias,
            const void* __restrict__ resid,
            void* __restrict__ C, void* __restrict__ C2, void* __restrict__ C3,
            int M, int N, int K, int lda, int ldc)
{
    constexpr int WM = BM / 2, WN = BN / 2, RM = WM / 16, RN = WN / 16;
    constexpr int PK = 40;
    __shared__ bf16_t As[BM * PK];
    __shared__ bf16_t Bs[BN * PK];

    const int t = threadIdx.x;
    const int m0 = blockIdx.y * BM, n0 = blockIdx.x * BN;
    const int ar = t >> 2, ac = (t & 3) * 8;
    const int lane = t & 63, wave = t >> 6;
    const int wm = (wave & 1) * WM, wn = (wave >> 1) * WN;
    const int fr = lane & 15, fq = (lane >> 4) * 8;

    f32x4 acc[RM][RN];
#pragma unroll
    for (int i = 0; i < RM; i++)
#pragma unroll
        for (int j = 0; j < RN; j++)
#pragma unroll
            for (int p = 0; p < 4; p++) acc[i][j][p] = 0.f;

    for (int kt = 0; kt < K; kt += 32) {
#pragma unroll
        for (int r = ar; r < BM; r += 64) {
            int kk = kt + ac;
            if (CONCAT && kk >= 768)
                ld8(&As[r * PK + ac], &A1[(long)(m0 + r) * lda + (kk - 768)]);
            else
                ld8(&As[r * PK + ac], &A0[(long)(m0 + r) * lda + kk]);
        }
#pragma unroll
        for (int r = ar; r < BN; r += 64)
            *(uint4*)&Bs[r * PK + ac] = *(const uint4*)&Bt[(long)(n0 + r) * K + kt + ac];
        __syncthreads();

        bf16x8v af[RM], bfr[RN];
#pragma unroll
        for (int i = 0; i < RM; i++)
            af[i] = *(const bf16x8v*)&As[(wm + i * 16 + fr) * PK + fq];
#pragma unroll
        for (int j = 0; j < RN; j++)
            bfr[j] = *(const bf16x8v*)&Bs[(wn + j * 16 + fr) * PK + fq];
#pragma unroll
        for (int i = 0; i < RM; i++)
#pragma unroll
            for (int j = 0; j < RN; j++)
                acc[i][j] = __builtin_amdgcn_mfma_f32_16x16x32_bf16(af[i], bfr[j], acc[i][j], 0, 0, 0);
        __syncthreads();
    }

    const int rq = (lane >> 4) * 4, cn = lane & 15;
#pragma unroll
    for (int i = 0; i < RM; i++)
#pragma unroll
        for (int j = 0; j < RN; j++) {
            int col = n0 + wn + j * 16 + cn;
            float bv = bias ? bias[col] : 0.f;
#pragma unroll
            for (int p = 0; p < 4; p++) {
                int row = m0 + wm + i * 16 + rq + p;
                float v = acc[i][j][p] + bv;
                if (ACT == 1) v = 1.f / (1.f + __expf(-v));
                if (ACT == 2) {
                    float u = 0.7978845608028654f * (v + 0.044715f * v * v * v);
                    v = 0.5f * v * (1.f + tanhf(u));
                }
                if (CMODE == 0) {
                    long idx = (long)row * ldc + col;
                    if (RES == 2) v += ((const float*)resid)[idx];
                    if (OUT == 0) ((bf16_t*)C)[idx] = (bf16_t)v;
                    else          ((float*)C)[idx] = v;
                } else {
                    int bb = row >> 10, ss = row & 1023;
                    int t3 = (CMODE == 4) ? (col / 768) : 0;
                    int cc = col - t3 * 768;
                    int hh = cc >> 6, dd = cc & 63;
                    long sidx = (((long)(bb * CH + hh) * 1024) + ss) * 64 + dd;
                    long tidx = (((long)(bb * CH + hh) * 64) + dd) * 1024 + ss;
                    if (CMODE == 2)      ((bf16_t*)C)[sidx] = (bf16_t)v;
                    else if (CMODE == 3) ((bf16_t*)C)[tidx] = (bf16_t)v;
                    else {
                        if (t3 == 0)      ((bf16_t*)C)[sidx]  = (bf16_t)v;
                        else if (t3 == 1) ((bf16_t*)C2)[sidx] = (bf16_t)v;
                        else              ((bf16_t*)C3)[tidx] = (bf16_t)v;
                    }
                }
            }
        }
}

// ===== fused flash attention, D=64, 64-wide key tiles =====
// MODE 0: self (scale 1, no mask, Sk=1024). MODE 1: enc (scale 1/8, int key mask
// replace -10000, Sk=1024). MODE 2: memory (Sk=128 padded, valid 100).
// Q [48,1024,64]; K: M<2 [48,1024,64], M2 mkt [12,128,64]; V: M<2 [48,64,1024],
// M2 mvt [12,64,128]. O merged [4,1024,768].
template<int MODE>
__global__ __launch_bounds__(256)
void flash_attn(const bf16_t* __restrict__ Q, const bf16_t* __restrict__ K,
                const bf16_t* __restrict__ V, const int* __restrict__ mask,
                bf16_t* __restrict__ O)
{
    __shared__ bf16_t Qs[128 * 72];   // also hosts P (wave-private 32-row chunks)
    __shared__ bf16_t Ks[64 * 72];
    __shared__ bf16_t Vs[64 * 72];

    const int t = threadIdx.x;
    const int lane = t & 63, wave = t >> 6;
    const int z = blockIdx.z;
    const int b = z / CH, h = z % CH;
    const int q0 = blockIdx.x * 128;

    const bf16_t* Qb = Q + (long)z * (1024 * 64) + (long)q0 * 64;
    const bf16_t* Kb = (MODE == 2) ? K + (long)h * (128 * 64) : K + (long)z * (1024 * 64);
    const bf16_t* Vb = (MODE == 2) ? V + (long)h * (64 * 128) : V + (long)z * (64 * 1024);
    const int ldv = (MODE == 2) ? 128 : 1024;
    const int NT = (MODE == 2) ? 2 : 16;

    {   // stage Q tile [128][64]
        int r = t >> 3, c = (t & 7) * 8;
        for (int rr = r; rr < 128; rr += 32)
            *(uint4*)&Qs[rr * 72 + c] = *(const uint4*)&Qb[(long)rr * 64 + c];
    }
    __syncthreads();

    const int fr = lane & 15, quad = lane >> 4;
    bf16x8v qf[2][2];
#pragma unroll
    for (int i = 0; i < 2; i++)
#pragma unroll
        for (int ks = 0; ks < 2; ks++)
            qf[i][ks] = *(const bf16x8v*)&Qs[(wave * 32 + i * 16 + fr) * 72 + quad * 8 + ks * 32];

    bf16_t* Ps = &Qs[wave * 32 * 72];   // wave-private P region (own rows only)

    f32x4 o[2][4];
    float mrow[2][4], lrow[2][4];
#pragma unroll
    for (int i = 0; i < 2; i++)
#pragma unroll
        for (int p = 0; p < 4; p++) { mrow[i][p] = -1e30f; lrow[i][p] = 0.f; }
#pragma unroll
    for (int i = 0; i < 2; i++)
#pragma unroll
        for (int j = 0; j < 4; j++)
#pragma unroll
            for (int p = 0; p < 4; p++) o[i][j][p] = 0.f;

    for (int kt = 0; kt < NT; kt++) {
        __syncthreads();
        {   // stage K [64 slots][64 d] and V^T [64 d][64 slots]
            int r = t >> 3, c = (t & 7) * 8;
            for (int rr = r; rr < 64; rr += 32)
                *(uint4*)&Ks[rr * 72 + c] = *(const uint4*)&Kb[(long)(kt * 64 + rr) * 64 + c];
            for (int rr = r; rr < 64; rr += 32)
                *(uint4*)&Vs[rr * 72 + c] = *(const uint4*)&Vb[(long)rr * ldv + kt * 64 + c];
        }
        __syncthreads();

        f32x4 s[2][4];
#pragma unroll
        for (int i = 0; i < 2; i++)
#pragma unroll
            for (int j = 0; j < 4; j++)
#pragma unroll
                for (int p = 0; p < 4; p++) s[i][j][p] = 0.f;
#pragma unroll
        for (int ks = 0; ks < 2; ks++) {
            bf16x8v bk[4];
#pragma unroll
            for (int j = 0; j < 4; j++)
                bk[j] = *(const bf16x8v*)&Ks[(j * 16 + fr) * 72 + quad * 8 + ks * 32];
#pragma unroll
            for (int i = 0; i < 2; i++)
#pragma unroll
                for (int j = 0; j < 4; j++)
                    s[i][j] = __builtin_amdgcn_mfma_f32_16x16x32_bf16(qf[i][ks], bk[j], s[i][j], 0, 0, 0);
        }
        if (MODE == 1) {
#pragma unroll
            for (int j = 0; j < 4; j++) {
                int mv = mask[(long)b * 1024 + kt * 64 + j * 16 + fr];
#pragma unroll
                for (int i = 0; i < 2; i++)
#pragma unroll
                    for (int p = 0; p < 4; p++)
                        s[i][j][p] = mv ? -10000.f : s[i][j][p] * 0.125f;
            }
        }
        if (MODE == 2) {
#pragma unroll
            for (int j = 0; j < 4; j++) {
                if (kt * 64 + j * 16 + fr >= 100)
#pragma unroll
                    for (int i = 0; i < 2; i++)
#pragma unroll
                        for (int p = 0; p < 4; p++) s[i][j][p] = -1e30f;
            }
        }
#pragma unroll
        for (int i = 0; i < 2; i++)
#pragma unroll
            for (int p = 0; p < 4; p++) {
                float tm = fmaxf(fmaxf(s[i][0][p], s[i][1][p]), fmaxf(s[i][2][p], s[i][3][p]));
                tm = fmaxf(tm, __shfl_xor(tm, 1, 64));
                tm = fmaxf(tm, __shfl_xor(tm, 2, 64));
                tm = fmaxf(tm, __shfl_xor(tm, 4, 64));
                tm = fmaxf(tm, __shfl_xor(tm, 8, 64));
                float mnew = fmaxf(mrow[i][p], tm);
                float alpha = __expf(mrow[i][p] - mnew);
                mrow[i][p] = mnew;
                float rs = 0.f;
#pragma unroll
                for (int j = 0; j < 4; j++) {
                    float e = __expf(s[i][j][p] - mnew);
                    s[i][j][p] = e;
                    rs += e;
                }
                rs += __shfl_xor(rs, 1, 64);
                rs += __shfl_xor(rs, 2, 64);
                rs += __shfl_xor(rs, 4, 64);
                rs += __shfl_xor(rs, 8, 64);
                lrow[i][p] = lrow[i][p] * alpha + rs;
#pragma unroll
                for (int j = 0; j < 4; j++) o[i][j][p] *= alpha;
            }
        // C-layout P -> A-layout via wave-private LDS (no barrier needed)
#pragma unroll
        for (int i = 0; i < 2; i++)
#pragma unroll
            for (int j = 0; j < 4; j++)
#pragma unroll
                for (int p = 0; p < 4; p++)
                    Ps[(i * 16 + quad * 4 + p) * 72 + j * 16 + fr] = (bf16_t)s[i][j][p];
#pragma unroll
        for (int ks = 0; ks < 2; ks++) {
            bf16x8v af[2], bv[4];
#pragma unroll
            for (int i = 0; i < 2; i++)
                af[i] = *(const bf16x8v*)&Ps[(i * 16 + fr) * 72 + quad * 8 + ks * 32];
#pragma unroll
            for (int j = 0; j < 4; j++)
                bv[j] = *(const bf16x8v*)&Vs[(j * 16 + fr) * 72 + quad * 8 + ks * 32];
#pragma unroll
            for (int i = 0; i < 2; i++)
#pragma unroll
                for (int j = 0; j < 4; j++)
                    o[i][j] = __builtin_amdgcn_mfma_f32_16x16x32_bf16(af[i], bv[j], o[i][j], 0, 0, 0);
        }
    }
#pragma unroll
    for (int i = 0; i < 2; i++)
#pragma unroll
        for (int p = 0; p < 4; p++) {
            float inv = 1.f / lrow[i][p];
            int srow = q0 + wave * 32 + i * 16 + quad * 4 + p;
            long base = ((long)b * 1024 + srow) * 768 + h * 64;
#pragma unroll
            for (int j = 0; j < 4; j++)
                O[base + j * 16 + fr] = (bf16_t)(o[i][j][p] * inv);
        }
}

// ===== LayerNorm rows of 768 (f32 in, bf16 out) =====
__global__ __launch_bounds__(256)
void ln_kernel(const float* __restrict__ in, bf16_t* __restrict__ out,
               const float* __restrict__ g, const float* __restrict__ b,
               int RC, long cstride)
{
    __shared__ float red[4];
    const int r = blockIdx.x, t = threadIdx.x;
    const long base = (long)(r / RC) * cstride + (long)(r % RC) * CE;
    float v0 = in[base + t], v1 = in[base + t + 256], v2 = in[base + t + 512];
    float s = v0 + v1 + v2;
    for (int m = 32; m; m >>= 1) s += __shfl_xor(s, m, 64);
    if ((t & 63) == 0) red[t >> 6] = s;
    __syncthreads();
    s = red[0] + red[1] + red[2] + red[3];
    __syncthreads();
    const float mu = s * (1.f / 768.f);
    float d0 = v0 - mu, d1 = v1 - mu, d2 = v2 - mu;
    float q = d0 * d0 + d1 * d1 + d2 * d2;
    for (int m = 32; m; m >>= 1) q += __shfl_xor(q, m, 64);
    if ((t & 63) == 0) red[t >> 6] = q;
    __syncthreads();
    q = red[0] + red[1] + red[2] + red[3];
    const float rstd = rsqrtf(q * (1.f / 768.f) + 1e-5f);
    const long ob = (long)r * CE;
    out[ob + t]       = (bf16_t)(g[t]       * d0 * rstd + b[t]);
    out[ob + t + 256] = (bf16_t)(g[t + 256] * d1 * rstd + b[t + 256]);
    out[ob + t + 512] = (bf16_t)(g[t + 512] * d2 * rstd + b[t + 512]);
}

// ===== elementwise =====
__global__ void blend_kernel(const bf16_t* __restrict__ al, bf16_t* __restrict__ a,
                             const bf16_t* __restrict__ a1)
{
    int idx = blockIdx.x * 256 + threadIdx.x;
    float g = (float)al[idx];
    a[idx] = (bf16_t)(g * (float)a[idx] + (1.f - g) * (float)a1[idx]);
}

__global__ void gate_part1(const bf16_t* __restrict__ al, const float* __restrict__ rf,
                           const bf16_t* __restrict__ eb, bf16_t* __restrict__ t1)
{
    int idx = blockIdx.x * 256 + threadIdx.x;
    float g = (float)al[idx];
    t1[idx] = (bf16_t)(g * rf[idx] + (1.f - g) * (float)eb[idx]);
}

__global__ void gate_part2(const bf16_t* __restrict__ al, float* __restrict__ rf,
                           const bf16_t* __restrict__ eb, const bf16_t* __restrict__ t1)
{
    int idx = blockIdx.x * 256 + threadIdx.x;
    float g = (float)al[idx];
    float v = (float)t1[idx] + g * rf[idx] + (1.f - g) * (float)eb[idx];
    rf[idx] = v * 0.7071067811865476f;
}

__global__ void zero_out(float* __restrict__ out)
{
    out[blockIdx.x * 256 + threadIdx.x] = 0.f;
}

__global__ void transpose_cast(const float* __restrict__ in, bf16_t* __restrict__ out,
                               int K, int N)
{   // in fp32 [K,N] -> out bf16 [N,K]
    __shared__ bf16_t tile[32][33];
    int n0 = blockIdx.x * 32, k0 = blockIdx.y * 32;
    int tx = threadIdx.x, ty = threadIdx.y;
    for (int i = ty; i < 32; i += 8)
        tile[i][tx] = (bf16_t)in[(long)(k0 + i) * N + n0 + tx];
    __syncthreads();
    for (int i = ty; i < 32; i += 8)
        out[(long)(n0 + i) * K + k0 + tx] = tile[tx][i];
}

__global__ void mem_gemm(const float* __restrict__ memf, const float* __restrict__ W,
                         const float* __restrict__ bias, bf16_t* __restrict__ out)
{
    int idx = blockIdx.x * 256 + threadIdx.x;
    int n = idx % 1536, m = idx / 1536;
    float acc = bias[n];
    for (int k = 0; k < 768; k++)
        acc += memf[m * 768 + k] * W[(long)k * 1536 + n];
    out[idx] = (bf16_t)acc;
}

__global__ void repack_mem(const bf16_t* __restrict__ mem, bf16_t* __restrict__ mkt,
                           bf16_t* __restrict__ mvt)
{
    int idx = blockIdx.x * 256 + threadIdx.x;
    int d = idx & 63;
    int slot = (idx >> 6) & 127;
    int h = idx >> 13;
    bf16_t kv = (slot < 100) ? mem[slot * 1536 + h * CD + d] : (bf16_t)0.f;
    bf16_t vv = (slot < 100) ? mem[slot * 1536 + CE + h * CD + d] : (bf16_t)0.f;
    mkt[idx] = kv;
    mvt[((long)h * 64 + d) * 128 + slot] = vv;
}

// ===================================================================================
extern "C" void kernel_launch(void* const* d_in, const int* in_sizes, int n_in,
                              void* d_out, int out_size, void* d_ws, size_t ws_size,
                              hipStream_t stream)
{
    (void)in_sizes; (void)n_in; (void)out_size;
    const float* x        = (const float*)d_in[0];
    const float* encf     = (const float*)d_in[1];
    const int*   maskenc  = (const int*)d_in[2];
    const float* ln1_g    = (const float*)d_in[3];
    const float* ln1_b    = (const float*)d_in[4];
    const float* ln2_g    = (const float*)d_in[5];
    const float* ln2_b    = (const float*)d_in[6];
    const float* c_attn_w = (const float*)d_in[7];
    const float* c_attn_b = (const float*)d_in[8];
    const float* aproj_w  = (const float*)d_in[9];
    const float* aproj_b  = (const float*)d_in[10];
    const float* memf     = (const float*)d_in[11];
    const float* mattn_w  = (const float*)d_in[12];
    const float* mattn_b  = (const float*)d_in[13];
    const float* malpha_w = (const float*)d_in[14];
    const float* malpha_b = (const float*)d_in[15];
    const float* fcq_w    = (const float*)d_in[16];
    const float* fcq_b    = (const float*)d_in[17];
    const float* fck_w    = (const float*)d_in[18];
    const float* fck_b    = (const float*)d_in[19];
    const float* fcv_w    = (const float*)d_in[20];
    const float* fcv_b    = (const float*)d_in[21];
    const float* eproj_w  = (const float*)d_in[22];
    const float* eproj_b  = (const float*)d_in[23];
    const float* fa1_w    = (const float*)d_in[24];
    const float* fa1_b    = (const float*)d_in[25];
    const float* fa2_w    = (const float*)d_in[26];
    const float* fa2_b    = (const float*)d_in[27];
    const float* mfc_w    = (const float*)d_in[28];
    const float* mfc_b    = (const float*)d_in[29];
    const float* mproj_w  = (const float*)d_in[30];
    const float* mproj_b  = (const float*)d_in[31];
    float* dout = (float*)d_out;

    size_t off = 0;
    auto alloc = [&](size_t bytes) -> void* {
        void* p = (char*)d_ws + off;
        off = (off + bytes + 255) & ~(size_t)255;
        return p;
    };
    const size_t SZ = (size_t)4096 * 768 * 2;
    bf16_t* wt_cattn  = (bf16_t*)alloc((size_t)2304 * 768 * 2);
    bf16_t* wt_aproj  = (bf16_t*)alloc((size_t)768 * 768 * 2);
    bf16_t* wt_malpha = (bf16_t*)alloc((size_t)768 * 1536 * 2);
    bf16_t* wt_fcq    = (bf16_t*)alloc((size_t)768 * 768 * 2);
    bf16_t* wt_fck    = (bf16_t*)alloc((size_t)768 * 768 * 2);
    bf16_t* wt_fcv    = (bf16_t*)alloc((size_t)768 * 768 * 2);
    bf16_t* wt_eproj  = (bf16_t*)alloc((size_t)768 * 768 * 2);
    bf16_t* wt_fa1    = (bf16_t*)alloc((size_t)768 * 1536 * 2);
    bf16_t* wt_fa2    = (bf16_t*)alloc((size_t)768 * 1536 * 2);
    bf16_t* wt_mfc    = (bf16_t*)alloc((size_t)3072 * 768 * 2);
    bf16_t* wt_mproj  = (bf16_t*)alloc((size_t)768 * 3072 * 2);
    bf16_t* membuf = (bf16_t*)alloc((size_t)100 * 1536 * 2);
    bf16_t* mkt    = (bf16_t*)alloc((size_t)CH * 128 * 64 * 2);
    bf16_t* mvt    = (bf16_t*)alloc((size_t)CH * 64 * 128 * 2);
    bf16_t* bufA   = (bf16_t*)alloc(SZ);
    bf16_t* qbuf   = (bf16_t*)alloc(SZ);
    bf16_t* kbuf   = (bf16_t*)alloc(SZ);
    bf16_t* vtbuf  = (bf16_t*)alloc(SZ);
    bf16_t* asbuf  = (bf16_t*)alloc(SZ);
    bf16_t* ebuf   = (bf16_t*)alloc(SZ);
    bf16_t* t1buf  = (bf16_t*)alloc(SZ);
    float*  residf = (float*)alloc((size_t)4096 * 768 * 4);

    if (off > ws_size) {   // finite diagnostic
        zero_out<<<12288, 256, 0, stream>>>(dout);
        return;
    }
    const size_t midbytes = (size_t)4096 * 3072 * 2;
    bf16_t* mid = nullptr;
    if (ws_size - off >= midbytes + 256) mid = (bf16_t*)alloc(midbytes);

    const dim3 blk(256);
    const long RB = (long)1024 * 768;

    auto T = [&](const float* w, bf16_t* wt, int Kd, int Nd) {
        transpose_cast<<<dim3(Nd / 32, Kd / 32), dim3(32, 8), 0, stream>>>(w, wt, Kd, Nd);
    };
    T(c_attn_w, wt_cattn, 768, 2304);
    T(aproj_w, wt_aproj, 768, 768);
    T(malpha_w, wt_malpha, 1536, 768);
    T(fcq_w, wt_fcq, 768, 768);
    T(fck_w, wt_fck, 768, 768);
    T(fcv_w, wt_fcv, 768, 768);
    T(eproj_w, wt_eproj, 768, 768);
    T(fa1_w, wt_fa1, 1536, 768);
    T(fa2_w, wt_fa2, 1536, 768);
    T(mfc_w, wt_mfc, 768, 3072);
    T(mproj_w, wt_mproj, 3072, 768);

    mem_gemm<<<600, blk, 0, stream>>>(memf, mattn_w, mattn_b, membuf);
    repack_mem<<<384, blk, 0, stream>>>(membuf, mkt, mvt);

    // h = LN1(x); qkv with fused head split
    ln_kernel<<<4096, blk, 0, stream>>>(x, bufA, ln1_g, ln1_b, 4096, 0);
    gemm_n<128,128,bf16_t,bf16_t,0,0,0,0,4><<<dim3(18, 32), blk, 0, stream>>>(
        bufA, nullptr, wt_cattn, c_attn_b, nullptr, qbuf, kbuf, vtbuf,
        4096, 2304, 768, 768, 0);

    // self + memory attention (fused flash)
    flash_attn<0><<<dim3(8, 1, 48), blk, 0, stream>>>(qbuf, kbuf, vtbuf, nullptr, asbuf);
    flash_attn<2><<<dim3(8, 1, 48), blk, 0, stream>>>(qbuf, mkt, mvt, nullptr, ebuf);

    // memory gate + blend + attn proj + residual
    gemm_n<64,128,bf16_t,bf16_t,1,1,0,0,0><<<dim3(6, 64), blk, 0, stream>>>(
        asbuf, ebuf, wt_malpha, malpha_b, nullptr, bufA, nullptr, nullptr,
        4096, 768, 1536, 768, 768);
    blend_kernel<<<12288, blk, 0, stream>>>(bufA, asbuf, ebuf);
    gemm_n<64,128,bf16_t,bf16_t,0,0,2,1,0><<<dim3(6, 64), blk, 0, stream>>>(
        asbuf, nullptr, wt_aproj, aproj_b, x, residf, nullptr, nullptr,
        4096, 768, 768, 768, 768);

    // cross attention
    ln_kernel<<<4096, blk, 0, stream>>>(residf, bufA, ln1_g, ln1_b, 4096, 0);
    gemm_n<64,128,bf16_t,bf16_t,0,0,0,0,2><<<dim3(6, 64), blk, 0, stream>>>(
        bufA, nullptr, wt_fcq, fcq_b, nullptr, qbuf, nullptr, nullptr,
        4096, 768, 768, 768, 0);

    for (int e = 0; e < 2; e++) {
        ln_kernel<<<4096, blk, 0, stream>>>(
            encf + (size_t)e * RB, bufA, ln1_g, ln1_b, 1024, (long)2 * RB);
        gemm_n<64,128,bf16_t,bf16_t,0,0,0,0,2><<<dim3(6, 64), blk, 0, stream>>>(
            bufA, nullptr, wt_fck, fck_b, nullptr, kbuf, nullptr, nullptr,
            4096, 768, 768, 768, 0);
        gemm_n<64,128,bf16_t,bf16_t,0,0,0,0,3><<<dim3(6, 64), blk, 0, stream>>>(
            bufA, nullptr, wt_fcv, fcv_b, nullptr, vtbuf, nullptr, nullptr,
            4096, 768, 768, 768, 0);
        flash_attn<1><<<dim3(8, 1, 48), blk, 0, stream>>>(qbuf, kbuf, vtbuf, maskenc, asbuf);
        gemm_n<64,128,bf16_t,bf16_t,0,0,0,0,0><<<dim3(6, 64), blk, 0, stream>>>(
            asbuf, nullptr, wt_eproj, eproj_b, nullptr, ebuf, nullptr, nullptr,
            4096, 768, 768, 768, 768);
        gemm_n<64,128,float,bf16_t,1,1,0,0,0><<<dim3(6, 64), blk, 0, stream>>>(
            residf, ebuf, (e == 0 ? wt_fa1 : wt_fa2), (e == 0 ? fa1_b : fa2_b), nullptr,
            bufA, nullptr, nullptr, 4096, 768, 1536, 768, 768);
        if (e == 0) gate_part1<<<12288, blk, 0, stream>>>(bufA, residf, ebuf, t1buf);
        else        gate_part2<<<12288, blk, 0, stream>>>(bufA, residf, ebuf, t1buf);
    }

    // MLP
    ln_kernel<<<4096, blk, 0, stream>>>(residf, bufA, ln2_g, ln2_b, 4096, 0);
    if (mid) {
        gemm_n<128,128,bf16_t,bf16_t,0,2,0,0,0><<<dim3(24, 32), blk, 0, stream>>>(
            bufA, nullptr, wt_mfc, mfc_b, nullptr, mid, nullptr, nullptr,
            4096, 3072, 768, 768, 3072);
        gemm_n<64,128,bf16_t,bf16_t,0,0,2,1,0><<<dim3(6, 64), blk, 0, stream>>>(
            mid, nullptr, wt_mproj, mproj_b, residf, dout, nullptr, nullptr,
            4096, 768, 3072, 3072, 768);
    } else {
        for (int mc = 0; mc < 4; mc++) {   // t1buf (dead) as [1024,3072] mid chunk
            gemm_n<128,128,bf16_t,bf16_t,0,2,0,0,0><<<dim3(24, 8), blk, 0, stream>>>(
                bufA + (long)mc * RB, nullptr, wt_mfc, mfc_b, nullptr, t1buf, nullptr, nullptr,
                1024, 3072, 768, 768, 3072);
            gemm_n<64,128,bf16_t,bf16_t,0,0,2,1,0><<<dim3(6, 16), blk, 0, stream>>>(
                t1buf, nullptr, wt_mproj, mproj_b, residf + (long)mc * RB,
                dout + (long)mc * RB, nullptr, nullptr,
                1024, 768, 3072, 3072, 768);
        }
    }
}

// Round 6
// 958.511 us; speedup vs baseline: 4.6213x; 1.1146x over previous
//
#include <hip/hip_runtime.h>

typedef __bf16 bf16_t;
typedef __bf16 bf16x8v __attribute__((ext_vector_type(8)));
typedef float f32x4 __attribute__((ext_vector_type(4)));

#define CB 4
#define CS 1024
#define CE 768
#define CH 12
#define CD 64

template<typename T>
__device__ __forceinline__ void ld8(bf16_t* dst, const T* src) {
    if constexpr (sizeof(T) == 2) {
        *(uint4*)dst = *(const uint4*)src;
    } else {
        const float4 a = *(const float4*)src;
        const float4 b = *(const float4*)(src + 4);
        bf16_t t0[8] = {(bf16_t)a.x, (bf16_t)a.y, (bf16_t)a.z, (bf16_t)a.w,
                        (bf16_t)b.x, (bf16_t)b.y, (bf16_t)b.z, (bf16_t)b.w};
        *(uint4*)dst = *(uint4*)t0;
    }
}

// ===== MFMA GEMM, B pre-transposed [N,K] bf16, BK=64 =====
// CONCAT: kk<768 -> A0, kk>=768 -> A1. ACT: 0 none,1 sigmoid,2 gelu.
// RES: 0 none, 2 += f32 resid. OUT: 0 bf16, 1 f32.
// CMODE: 0 normal(ldc); 2 split [b,H,s,d]; 3 split [b,H,d,s];
//        4 qkv->C,C2,C3; 5 kv: k->C [bb,H,s,d], v->C2 [bb,H,d,s] (bias2 for v).
template<int BM, int BN, typename TA0, typename TA1, int CONCAT, int ACT, int RES,
         int OUT, int CMODE>
__global__ __launch_bounds__(256)
void gemm_n(const TA0* __restrict__ A0, const TA1* __restrict__ A1,
            const bf16_t* __restrict__ Bt, const float* __restrict__ bias,
            const float* __restrict__ bias2, const void* __restrict__ resid,
            void* __restrict__ C, void* __restrict__ C2, void* __restrict__ C3,
            int M, int N, int K, int lda, int ldc)
{
    constexpr int WM = BM / 2, WN = BN / 2, RM = WM / 16, RN = WN / 16;
    constexpr int PK = 72;   // 64 + 8 pad
    __shared__ bf16_t As[BM * PK];
    __shared__ bf16_t Bs[BN * PK];

    const int t = threadIdx.x;
    const int m0 = blockIdx.y * BM, n0 = blockIdx.x * BN;
    const int r0 = t >> 3, c0 = (t & 7) * 8;
    const int lane = t & 63, wave = t >> 6;
    const int wm = (wave & 1) * WM, wn = (wave >> 1) * WN;
    const int fr = lane & 15, quad = lane >> 4;

    f32x4 acc[RM][RN];
#pragma unroll
    for (int i = 0; i < RM; i++)
#pragma unroll
        for (int j = 0; j < RN; j++)
#pragma unroll
            for (int p = 0; p < 4; p++) acc[i][j][p] = 0.f;

    for (int kt = 0; kt < K; kt += 64) {
#pragma unroll
        for (int r = r0; r < BM; r += 32) {
            int kk = kt + c0;
            if (CONCAT && kk >= 768)
                ld8(&As[r * PK + c0], &A1[(long)(m0 + r) * lda + (kk - 768)]);
            else
                ld8(&As[r * PK + c0], &A0[(long)(m0 + r) * lda + kk]);
        }
#pragma unroll
        for (int r = r0; r < BN; r += 32)
            *(uint4*)&Bs[r * PK + c0] = *(const uint4*)&Bt[(long)(n0 + r) * K + kt + c0];
        __syncthreads();

        bf16x8v af[RM][2], bfr[RN][2];
#pragma unroll
        for (int i = 0; i < RM; i++)
#pragma unroll
            for (int ks = 0; ks < 2; ks++)
                af[i][ks] = *(const bf16x8v*)&As[(wm + i * 16 + fr) * PK + quad * 8 + ks * 32];
#pragma unroll
        for (int j = 0; j < RN; j++)
#pragma unroll
            for (int ks = 0; ks < 2; ks++)
                bfr[j][ks] = *(const bf16x8v*)&Bs[(wn + j * 16 + fr) * PK + quad * 8 + ks * 32];
#pragma unroll
        for (int ks = 0; ks < 2; ks++)
#pragma unroll
            for (int i = 0; i < RM; i++)
#pragma unroll
                for (int j = 0; j < RN; j++)
                    acc[i][j] = __builtin_amdgcn_mfma_f32_16x16x32_bf16(af[i][ks], bfr[j][ks], acc[i][j], 0, 0, 0);
        __syncthreads();
    }

    const int rq = quad * 4, cn = fr;
#pragma unroll
    for (int i = 0; i < RM; i++)
#pragma unroll
        for (int j = 0; j < RN; j++) {
            int col = n0 + wn + j * 16 + cn;
            int t3 = (CMODE >= 4) ? (col / 768) : 0;
            int cc = col - t3 * 768;
            float bv = 0.f;
            if (CMODE == 5) bv = t3 ? bias2[cc] : bias[cc];
            else if (bias)  bv = bias[col];
#pragma unroll
            for (int p = 0; p < 4; p++) {
                int row = m0 + wm + i * 16 + rq + p;
                float v = acc[i][j][p] + bv;
                if (ACT == 1) v = 1.f / (1.f + __expf(-v));
                if (ACT == 2) {
                    float u = 0.7978845608028654f * (v + 0.044715f * v * v * v);
                    v = 0.5f * v * (1.f + tanhf(u));
                }
                if (CMODE == 0) {
                    long idx = (long)row * ldc + col;
                    if (RES == 2) v += ((const float*)resid)[idx];
                    if (OUT == 0) ((bf16_t*)C)[idx] = (bf16_t)v;
                    else          ((float*)C)[idx] = v;
                } else {
                    int bb = row >> 10, ss = row & 1023;
                    int hh = cc >> 6, dd = cc & 63;
                    long sidx = (((long)(bb * CH + hh) * 1024) + ss) * 64 + dd;
                    long tidx = (((long)(bb * CH + hh) * 64) + dd) * 1024 + ss;
                    if (CMODE == 2)      ((bf16_t*)C)[sidx] = (bf16_t)v;
                    else if (CMODE == 3) ((bf16_t*)C)[tidx] = (bf16_t)v;
                    else if (CMODE == 5) {
                        if (t3 == 0) ((bf16_t*)C)[sidx]  = (bf16_t)v;
                        else         ((bf16_t*)C2)[tidx] = (bf16_t)v;
                    } else {
                        if (t3 == 0)      ((bf16_t*)C)[sidx]  = (bf16_t)v;
                        else if (t3 == 1) ((bf16_t*)C2)[sidx] = (bf16_t)v;
                        else              ((bf16_t*)C3)[tidx] = (bf16_t)v;
                    }
                }
            }
        }
}

// ===== fused flash attention, D=64, 64-row Q tiles, 64-wide key tiles =====
// MODE 0: self (scale 1, Sk=1024). MODE 1: enc (scale 1/8, key mask, Sk=1024).
// MODE 2: memory (Sk=128 padded, valid 100).
template<int MODE>
__global__ __launch_bounds__(256)
void flash_attn(const bf16_t* __restrict__ Q, const bf16_t* __restrict__ K,
                const bf16_t* __restrict__ V, const int* __restrict__ mask,
                bf16_t* __restrict__ O)
{
    __shared__ bf16_t Qs[64 * 72];   // wave-private 16-row strips, reused for P
    __shared__ bf16_t Ks[64 * 72];
    __shared__ bf16_t Vs[64 * 72];

    const int t = threadIdx.x;
    const int lane = t & 63, wave = t >> 6;
    const int z = blockIdx.z;
    const int b = z / CH, h = z % CH;
    const int q0 = blockIdx.x * 64;

    const bf16_t* Qb = Q + (long)z * (1024 * 64) + (long)q0 * 64;
    const bf16_t* Kb = (MODE == 2) ? K + (long)h * (128 * 64) : K + (long)z * (1024 * 64);
    const bf16_t* Vb = (MODE == 2) ? V + (long)h * (64 * 128) : V + (long)z * (64 * 1024);
    const int ldv = (MODE == 2) ? 128 : 1024;
    const int NT = (MODE == 2) ? 2 : 16;

    const int r0 = t >> 3, c0 = (t & 7) * 8;
    for (int rr = r0; rr < 64; rr += 32)
        *(uint4*)&Qs[rr * 72 + c0] = *(const uint4*)&Qb[(long)rr * 64 + c0];
    __syncthreads();

    const int fr = lane & 15, quad = lane >> 4;
    bf16x8v qf[2];
#pragma unroll
    for (int ks = 0; ks < 2; ks++)
        qf[ks] = *(const bf16x8v*)&Qs[(wave * 16 + fr) * 72 + quad * 8 + ks * 32];

    bf16_t* Ps = &Qs[wave * 16 * 72];

    f32x4 o[4];
    float mrow[4], lrow[4];
#pragma unroll
    for (int p = 0; p < 4; p++) { mrow[p] = -1e30f; lrow[p] = 0.f; }
#pragma unroll
    for (int j = 0; j < 4; j++)
#pragma unroll
        for (int p = 0; p < 4; p++) o[j][p] = 0.f;

    for (int kt = 0; kt < NT; kt++) {
        __syncthreads();
        for (int rr = r0; rr < 64; rr += 32)
            *(uint4*)&Ks[rr * 72 + c0] = *(const uint4*)&Kb[(long)(kt * 64 + rr) * 64 + c0];
        for (int rr = r0; rr < 64; rr += 32)
            *(uint4*)&Vs[rr * 72 + c0] = *(const uint4*)&Vb[(long)rr * ldv + kt * 64 + c0];
        __syncthreads();

        f32x4 s[4];
#pragma unroll
        for (int j = 0; j < 4; j++)
#pragma unroll
            for (int p = 0; p < 4; p++) s[j][p] = 0.f;
#pragma unroll
        for (int ks = 0; ks < 2; ks++) {
            bf16x8v bk[4];
#pragma unroll
            for (int j = 0; j < 4; j++)
                bk[j] = *(const bf16x8v*)&Ks[(j * 16 + fr) * 72 + quad * 8 + ks * 32];
#pragma unroll
            for (int j = 0; j < 4; j++)
                s[j] = __builtin_amdgcn_mfma_f32_16x16x32_bf16(qf[ks], bk[j], s[j], 0, 0, 0);
        }
        if (MODE == 1) {
#pragma unroll
            for (int j = 0; j < 4; j++) {
                int mv = mask[(long)b * 1024 + kt * 64 + j * 16 + fr];
#pragma unroll
                for (int p = 0; p < 4; p++)
                    s[j][p] = mv ? -10000.f : s[j][p] * 0.125f;
            }
        }
        if (MODE == 2) {
#pragma unroll
            for (int j = 0; j < 4; j++)
                if (kt * 64 + j * 16 + fr >= 100)
#pragma unroll
                    for (int p = 0; p < 4; p++) s[j][p] = -1e30f;
        }
#pragma unroll
        for (int p = 0; p < 4; p++) {
            float tm = fmaxf(fmaxf(s[0][p], s[1][p]), fmaxf(s[2][p], s[3][p]));
            tm = fmaxf(tm, __shfl_xor(tm, 1, 64));
            tm = fmaxf(tm, __shfl_xor(tm, 2, 64));
            tm = fmaxf(tm, __shfl_xor(tm, 4, 64));
            tm = fmaxf(tm, __shfl_xor(tm, 8, 64));
            float mnew = fmaxf(mrow[p], tm);
            float alpha = __expf(mrow[p] - mnew);
            mrow[p] = mnew;
            float rs = 0.f;
#pragma unroll
            for (int j = 0; j < 4; j++) {
                float e = __expf(s[j][p] - mnew);
                s[j][p] = e;
                rs += e;
            }
            rs += __shfl_xor(rs, 1, 64);
            rs += __shfl_xor(rs, 2, 64);
            rs += __shfl_xor(rs, 4, 64);
            rs += __shfl_xor(rs, 8, 64);
            lrow[p] = lrow[p] * alpha + rs;
#pragma unroll
            for (int j = 0; j < 4; j++) o[j][p] *= alpha;
        }
        // C-layout P -> A-layout via wave-private LDS
#pragma unroll
        for (int j = 0; j < 4; j++)
#pragma unroll
            for (int p = 0; p < 4; p++)
                Ps[(quad * 4 + p) * 72 + j * 16 + fr] = (bf16_t)s[j][p];
#pragma unroll
        for (int ks = 0; ks < 2; ks++) {
            bf16x8v af = *(const bf16x8v*)&Ps[fr * 72 + quad * 8 + ks * 32];
            bf16x8v bv[4];
#pragma unroll
            for (int j = 0; j < 4; j++)
                bv[j] = *(const bf16x8v*)&Vs[(j * 16 + fr) * 72 + quad * 8 + ks * 32];
#pragma unroll
            for (int j = 0; j < 4; j++)
                o[j] = __builtin_amdgcn_mfma_f32_16x16x32_bf16(af, bv[j], o[j], 0, 0, 0);
        }
    }
#pragma unroll
    for (int p = 0; p < 4; p++) {
        float inv = 1.f / lrow[p];
        int srow = q0 + wave * 16 + quad * 4 + p;
        long base = ((long)b * 1024 + srow) * 768 + h * 64;
#pragma unroll
        for (int j = 0; j < 4; j++)
            O[base + j * 16 + fr] = (bf16_t)(o[j][p] * inv);
    }
}

// ===== LayerNorm rows of 768 (f32 in, bf16 out) =====
__device__ __forceinline__ void ln_body(const float* in, bf16_t* out,
                                        const float* g, const float* b,
                                        long base, long ob, int t)
{
    __shared__ float red[4];
    float v0 = in[base + t], v1 = in[base + t + 256], v2 = in[base + t + 512];
    float s = v0 + v1 + v2;
    for (int m = 32; m; m >>= 1) s += __shfl_xor(s, m, 64);
    if ((t & 63) == 0) red[t >> 6] = s;
    __syncthreads();
    s = red[0] + red[1] + red[2] + red[3];
    __syncthreads();
    const float mu = s * (1.f / 768.f);
    float d0 = v0 - mu, d1 = v1 - mu, d2 = v2 - mu;
    float q = d0 * d0 + d1 * d1 + d2 * d2;
    for (int m = 32; m; m >>= 1) q += __shfl_xor(q, m, 64);
    if ((t & 63) == 0) red[t >> 6] = q;
    __syncthreads();
    q = red[0] + red[1] + red[2] + red[3];
    const float rstd = rsqrtf(q * (1.f / 768.f) + 1e-5f);
    out[ob + t]       = (bf16_t)(g[t]       * d0 * rstd + b[t]);
    out[ob + t + 256] = (bf16_t)(g[t + 256] * d1 * rstd + b[t + 256]);
    out[ob + t + 512] = (bf16_t)(g[t + 512] * d2 * rstd + b[t + 512]);
}

__global__ __launch_bounds__(256)
void ln_kernel(const float* __restrict__ in, bf16_t* __restrict__ out,
               const float* __restrict__ g, const float* __restrict__ b)
{
    const int r = blockIdx.x;
    ln_body(in, out, g, b, (long)r * CE, (long)r * CE, threadIdx.x);
}

__global__ __launch_bounds__(256)
void ln_enc(const float* __restrict__ encf, bf16_t* __restrict__ out,
            const float* __restrict__ g, const float* __restrict__ b)
{   // out row r = e*4096 + bb*1024 + s  <-  encf[(bb*2+e)*1024 + s]
    const int r = blockIdx.x;
    const int e = r >> 12, rr = r & 4095, bb = rr >> 10, s = rr & 1023;
    ln_body(encf, out, g, b, ((long)(bb * 2 + e) * 1024 + s) * CE, (long)r * CE, threadIdx.x);
}

// ===== elementwise =====
__global__ void blend_kernel(const bf16_t* __restrict__ al, bf16_t* __restrict__ a,
                             const bf16_t* __restrict__ a1)
{
    int idx = blockIdx.x * 256 + threadIdx.x;
    float g = (float)al[idx];
    a[idx] = (bf16_t)(g * (float)a[idx] + (1.f - g) * (float)a1[idx]);
}

__global__ void fuse_gates2(const bf16_t* __restrict__ gal, const bf16_t* __restrict__ eo,
                            float* __restrict__ rf)
{
    const long SZel = (long)4096 * 768;
    long idx = (long)blockIdx.x * 256 + threadIdx.x;
    float g1 = (float)gal[idx], g2 = (float)gal[idx + SZel];
    float e1 = (float)eo[idx],  e2 = (float)eo[idx + SZel];
    float r = rf[idx];
    float v = g1 * r + (1.f - g1) * e1 + g2 * r + (1.f - g2) * e2;
    rf[idx] = v * 0.7071067811865476f;
}

__global__ void zero_out(float* __restrict__ out)
{
    out[blockIdx.x * 256 + threadIdx.x] = 0.f;
}

__global__ void transpose_cast(const float* __restrict__ in, bf16_t* __restrict__ out,
                               int K, int N)
{
    __shared__ bf16_t tile[32][33];
    int n0 = blockIdx.x * 32, k0 = blockIdx.y * 32;
    int tx = threadIdx.x, ty = threadIdx.y;
    for (int i = ty; i < 32; i += 8)
        tile[i][tx] = (bf16_t)in[(long)(k0 + i) * N + n0 + tx];
    __syncthreads();
    for (int i = ty; i < 32; i += 8)
        out[(long)(n0 + i) * K + k0 + tx] = tile[tx][i];
}

__global__ void mem_gemm(const float* __restrict__ memf, const float* __restrict__ W,
                         const float* __restrict__ bias, bf16_t* __restrict__ out)
{
    int idx = blockIdx.x * 256 + threadIdx.x;
    int n = idx % 1536, m = idx / 1536;
    float acc = bias[n];
    for (int k = 0; k < 768; k++)
        acc += memf[m * 768 + k] * W[(long)k * 1536 + n];
    out[idx] = (bf16_t)acc;
}

__global__ void repack_mem(const bf16_t* __restrict__ mem, bf16_t* __restrict__ mkt,
                           bf16_t* __restrict__ mvt)
{
    int idx = blockIdx.x * 256 + threadIdx.x;
    int d = idx & 63;
    int slot = (idx >> 6) & 127;
    int h = idx >> 13;
    bf16_t kv = (slot < 100) ? mem[slot * 1536 + h * CD + d] : (bf16_t)0.f;
    bf16_t vv = (slot < 100) ? mem[slot * 1536 + CE + h * CD + d] : (bf16_t)0.f;
    mkt[idx] = kv;
    mvt[((long)h * 64 + d) * 128 + slot] = vv;
}

// ===================================================================================
extern "C" void kernel_launch(void* const* d_in, const int* in_sizes, int n_in,
                              void* d_out, int out_size, void* d_ws, size_t ws_size,
                              hipStream_t stream)
{
    (void)in_sizes; (void)n_in; (void)out_size;
    const float* x        = (const float*)d_in[0];
    const float* encf     = (const float*)d_in[1];
    const int*   maskenc  = (const int*)d_in[2];
    const float* ln1_g    = (const float*)d_in[3];
    const float* ln1_b    = (const float*)d_in[4];
    const float* ln2_g    = (const float*)d_in[5];
    const float* ln2_b    = (const float*)d_in[6];
    const float* c_attn_w = (const float*)d_in[7];
    const float* c_attn_b = (const float*)d_in[8];
    const float* aproj_w  = (const float*)d_in[9];
    const float* aproj_b  = (const float*)d_in[10];
    const float* memf     = (const float*)d_in[11];
    const float* mattn_w  = (const float*)d_in[12];
    const float* mattn_b  = (const float*)d_in[13];
    const float* malpha_w = (const float*)d_in[14];
    const float* malpha_b = (const float*)d_in[15];
    const float* fcq_w    = (const float*)d_in[16];
    const float* fcq_b    = (const float*)d_in[17];
    const float* fck_w    = (const float*)d_in[18];
    const float* fck_b    = (const float*)d_in[19];
    const float* fcv_w    = (const float*)d_in[20];
    const float* fcv_b    = (const float*)d_in[21];
    const float* eproj_w  = (const float*)d_in[22];
    const float* eproj_b  = (const float*)d_in[23];
    const float* fa1_w    = (const float*)d_in[24];
    const float* fa1_b    = (const float*)d_in[25];
    const float* fa2_w    = (const float*)d_in[26];
    const float* fa2_b    = (const float*)d_in[27];
    const float* mfc_w    = (const float*)d_in[28];
    const float* mfc_b    = (const float*)d_in[29];
    const float* mproj_w  = (const float*)d_in[30];
    const float* mproj_b  = (const float*)d_in[31];
    float* dout = (float*)d_out;

    size_t off = 0;
    auto alloc = [&](size_t bytes) -> void* {
        void* p = (char*)d_ws + off;
        off = (off + bytes + 255) & ~(size_t)255;
        return p;
    };
    const size_t SZ = (size_t)4096 * 768 * 2;
    const long SZel = (long)4096 * 768;
    bf16_t* wt_cattn  = (bf16_t*)alloc((size_t)2304 * 768 * 2);
    bf16_t* wt_aproj  = (bf16_t*)alloc((size_t)768 * 768 * 2);
    bf16_t* wt_malpha = (bf16_t*)alloc((size_t)768 * 1536 * 2);
    bf16_t* wt_fcq    = (bf16_t*)alloc((size_t)768 * 768 * 2);
    bf16_t* wt_fck    = (bf16_t*)alloc((size_t)768 * 768 * 2);   // adjacent:
    bf16_t* wt_fcv    = (bf16_t*)alloc((size_t)768 * 768 * 2);   // wt_fck..wt_fcv = [1536,768]
    bf16_t* wt_eproj  = (bf16_t*)alloc((size_t)768 * 768 * 2);
    bf16_t* wt_fa1    = (bf16_t*)alloc((size_t)768 * 1536 * 2);
    bf16_t* wt_fa2    = (bf16_t*)alloc((size_t)768 * 1536 * 2);
    bf16_t* wt_mfc    = (bf16_t*)alloc((size_t)3072 * 768 * 2);
    bf16_t* wt_mproj  = (bf16_t*)alloc((size_t)768 * 3072 * 2);
    bf16_t* membuf = (bf16_t*)alloc((size_t)100 * 1536 * 2);
    bf16_t* mkt    = (bf16_t*)alloc((size_t)CH * 128 * 64 * 2);
    bf16_t* mvt    = (bf16_t*)alloc((size_t)CH * 64 * 128 * 2);
    bf16_t* bufA   = (bf16_t*)alloc(SZ);        // LN out [4096,768]
    bf16_t* qbuf   = (bf16_t*)alloc(SZ);        // q [4,12,1024,64]
    bf16_t* kbuf   = (bf16_t*)alloc(2 * SZ);    // k [2|4,12,1024,64] / gates / mid lo
    bf16_t* vtbuf  = (bf16_t*)alloc(2 * SZ);    // v [2|4,12,64,1024] / mid hi
    bf16_t* asbuf  = (bf16_t*)alloc(2 * SZ);    // attn out: self[0]+mem[1] / enc e0,e1
    bf16_t* bufB   = (bf16_t*)alloc(2 * SZ);    // enc LN [8192,768] / eproj out
    float*  residf = (float*)alloc((size_t)4096 * 768 * 4);

    if (off > ws_size) {   // finite diagnostic
        zero_out<<<12288, 256, 0, stream>>>(dout);
        return;
    }
    bf16_t* mid = kbuf;          // [4096,3072] spans kbuf+vtbuf (both dead at MLP)
    bf16_t* galbuf = kbuf;       // stacked gate outputs [8192,768] (dead k)
    bf16_t* eobuf = bufB;        // stacked eproj outputs [8192,768]

    const dim3 blk(256);

    auto T = [&](const float* w, bf16_t* wt, int Kd, int Nd) {
        transpose_cast<<<dim3(Nd / 32, Kd / 32), dim3(32, 8), 0, stream>>>(w, wt, Kd, Nd);
    };
    T(c_attn_w, wt_cattn, 768, 2304);
    T(aproj_w, wt_aproj, 768, 768);
    T(malpha_w, wt_malpha, 1536, 768);
    T(fcq_w, wt_fcq, 768, 768);
    T(fck_w, wt_fck, 768, 768);
    T(fcv_w, wt_fcv, 768, 768);
    T(eproj_w, wt_eproj, 768, 768);
    T(fa1_w, wt_fa1, 1536, 768);
    T(fa2_w, wt_fa2, 1536, 768);
    T(mfc_w, wt_mfc, 768, 3072);
    T(mproj_w, wt_mproj, 3072, 768);

    mem_gemm<<<600, blk, 0, stream>>>(memf, mattn_w, mattn_b, membuf);
    repack_mem<<<384, blk, 0, stream>>>(membuf, mkt, mvt);

    // h = LN1(x); qkv with fused head split
    ln_kernel<<<4096, blk, 0, stream>>>(x, bufA, ln1_g, ln1_b);
    gemm_n<128,128,bf16_t,bf16_t,0,0,0,0,4><<<dim3(18, 32), blk, 0, stream>>>(
        bufA, nullptr, wt_cattn, c_attn_b, nullptr, nullptr, qbuf, kbuf, vtbuf,
        4096, 2304, 768, 768, 0);

    // self + memory attention
    flash_attn<0><<<dim3(16, 1, 48), blk, 0, stream>>>(qbuf, kbuf, vtbuf, nullptr, asbuf);
    flash_attn<2><<<dim3(16, 1, 48), blk, 0, stream>>>(qbuf, mkt, mvt, nullptr, asbuf + SZel);

    // memory gate (concat fused) + blend + attn proj + residual
    gemm_n<64,64,bf16_t,bf16_t,1,1,0,0,0><<<dim3(12, 64), blk, 0, stream>>>(
        asbuf, asbuf + SZel, wt_malpha, malpha_b, nullptr, nullptr, bufA, nullptr, nullptr,
        4096, 768, 1536, 768, 768);
    blend_kernel<<<12288, blk, 0, stream>>>(bufA, asbuf, asbuf + SZel);
    gemm_n<64,64,bf16_t,bf16_t,0,0,2,1,0><<<dim3(12, 64), blk, 0, stream>>>(
        asbuf, nullptr, wt_aproj, aproj_b, nullptr, x, residf, nullptr, nullptr,
        4096, 768, 768, 768, 768);

    // cross attention: q once; both encoders stacked (M=8192)
    ln_kernel<<<4096, blk, 0, stream>>>(residf, bufA, ln1_g, ln1_b);
    gemm_n<64,64,bf16_t,bf16_t,0,0,0,0,2><<<dim3(12, 64), blk, 0, stream>>>(
        bufA, nullptr, wt_fcq, fcq_b, nullptr, nullptr, qbuf, nullptr, nullptr,
        4096, 768, 768, 768, 0);

    ln_enc<<<8192, blk, 0, stream>>>(encf, bufB, ln1_g, ln1_b);
    gemm_n<64,128,bf16_t,bf16_t,0,0,0,0,5><<<dim3(12, 128), blk, 0, stream>>>(
        bufB, nullptr, wt_fck, fck_b, fcv_b, nullptr, kbuf, vtbuf, nullptr,
        8192, 1536, 768, 768, 0);
    flash_attn<1><<<dim3(16, 1, 48), blk, 0, stream>>>(
        qbuf, kbuf, vtbuf, maskenc, asbuf);
    flash_attn<1><<<dim3(16, 1, 48), blk, 0, stream>>>(
        qbuf, kbuf + SZel, vtbuf + SZel, maskenc, asbuf + SZel);
    gemm_n<64,64,bf16_t,bf16_t,0,0,0,0,0><<<dim3(12, 128), blk, 0, stream>>>(
        asbuf, nullptr, wt_eproj, eproj_b, nullptr, nullptr, eobuf, nullptr, nullptr,
        8192, 768, 768, 768, 768);
    gemm_n<64,64,float,bf16_t,1,1,0,0,0><<<dim3(12, 64), blk, 0, stream>>>(
        residf, eobuf, wt_fa1, fa1_b, nullptr, nullptr, galbuf, nullptr, nullptr,
        4096, 768, 1536, 768, 768);
    gemm_n<64,64,float,bf16_t,1,1,0,0,0><<<dim3(12, 64), blk, 0, stream>>>(
        residf, eobuf + SZel, wt_fa2, fa2_b, nullptr, nullptr, galbuf + SZel, nullptr, nullptr,
        4096, 768, 1536, 768, 768);
    fuse_gates2<<<12288, blk, 0, stream>>>(galbuf, eobuf, residf);

    // MLP
    ln_kernel<<<4096, blk, 0, stream>>>(residf, bufA, ln2_g, ln2_b);
    gemm_n<128,128,bf16_t,bf16_t,0,2,0,0,0><<<dim3(24, 32), blk, 0, stream>>>(
        bufA, nullptr, wt_mfc, mfc_b, nullptr, nullptr, mid, nullptr, nullptr,
        4096, 3072, 768, 768, 3072);
    gemm_n<64,64,bf16_t,bf16_t,0,0,2,1,0><<<dim3(12, 64), blk, 0, stream>>>(
        mid, nullptr, wt_mproj, mproj_b, nullptr, residf, dout, nullptr, nullptr,
        4096, 768, 3072, 3072, 768);
}